// Round 12
// baseline (1066.188 us; speedup 1.0000x reference)
//
#include <hip/hip_runtime.h>
#include <math.h>

#define N_NODES 20000
#define N_EDGES 320000
#define HH      256
#define GG      128
#define FE      16
#define MPAD    20032   // N_NODES rounded up to 64

typedef short  bf16x8 __attribute__((ext_vector_type(8)));
typedef float  f32x4  __attribute__((ext_vector_type(4)));
typedef unsigned short ushort_t;

__device__ __forceinline__ float fast_rcp(float x) {
    return __builtin_amdgcn_rcpf(x);
}
__device__ __forceinline__ float fast_sigmoid(float x) {
    return fast_rcp(1.f + __expf(-x));
}
__device__ __forceinline__ float sig_tanh(float zi, float zg) {
    float u = __expf(-zi);       // sigmoid = 1/(1+u)
    float v = __expf(2.f * zg);  // tanh = (v-1)/(v+1)
    return (v - 1.f) * fast_rcp((1.f + u) * (v + 1.f));
}
// bf16 (RNE) helpers on raw bits
__device__ __forceinline__ ushort_t f2bf(float x) {
    unsigned u = __float_as_uint(x);
    return (ushort_t)((u + 0x7fffu + ((u >> 16) & 1u)) >> 16);
}
__device__ __forceinline__ float bf2f(ushort_t h) {
    return __uint_as_float(((unsigned)h) << 16);
}

// ---------------------------------------------------------------------------
// CSR build: histogram / two-level scan / permuting scatter
// ---------------------------------------------------------------------------
__global__ void hist_k(const int* __restrict__ dst, int* __restrict__ cnt) {
    int e = blockIdx.x * blockDim.x + threadIdx.x;
    if (e < N_EDGES) atomicAdd(&cnt[dst[e]], 1);
}

__global__ __launch_bounds__(256) void scan1_k(const int* __restrict__ cnt,
                                               int* __restrict__ ex,
                                               int* __restrict__ bsum) {
    int b = blockIdx.x, t = threadIdx.x;
    int i = b * 256 + t;
    int v = (i < N_NODES) ? cnt[i] : 0;
    int lane = t & 63, w = t >> 6;
    int incl = v;
#pragma unroll
    for (int off = 1; off < 64; off <<= 1) {
        int u = __shfl_up(incl, off);
        if (lane >= off) incl += u;
    }
    __shared__ int wsum[4];
    if (lane == 63) wsum[w] = incl;
    __syncthreads();
    int woff = 0;
#pragma unroll
    for (int j = 0; j < 4; ++j)
        if (j < w) woff += wsum[j];
    if (i < N_NODES) ex[i] = woff + incl - v;
    if (t == 255) bsum[b] = woff + incl;
}

__global__ __launch_bounds__(128) void scan2_k(int* __restrict__ bsum, int nb) {
    int t = threadIdx.x;
    int v = (t < nb) ? bsum[t] : 0;
    int lane = t & 63, w = t >> 6;
    int incl = v;
#pragma unroll
    for (int off = 1; off < 64; off <<= 1) {
        int u = __shfl_up(incl, off);
        if (lane >= off) incl += u;
    }
    __shared__ int wsum[2];
    if (lane == 63) wsum[w] = incl;
    __syncthreads();
    int woff = (w == 1) ? wsum[0] : 0;
    if (t < nb) bsum[t] = woff + incl - v;
}

__global__ __launch_bounds__(256) void scan3_k(const int* __restrict__ cnt,
                                               const int* __restrict__ bsum,
                                               int* __restrict__ rowst,
                                               int* __restrict__ cursor) {
    int b = blockIdx.x, t = threadIdx.x;
    int i = b * 256 + t;
    if (i < N_NODES) {
        int v = rowst[i] + bsum[b];
        rowst[i] = v;
        cursor[i] = v;
        if (i == N_NODES - 1) rowst[N_NODES] = v + cnt[i];
    }
}

// scatter edges into CSR order; emit src and bf16 hi/lo attr planes [E,16]
__global__ void scatter_k(const int* __restrict__ src,
                          const int* __restrict__ dst,
                          const float* __restrict__ eattr,
                          int* __restrict__ cursor, int* __restrict__ srcs,
                          ushort_t* __restrict__ eaH,
                          ushort_t* __restrict__ eaL) {
    int e = blockIdx.x * blockDim.x + threadIdx.x;
    if (e >= N_EDGES) return;
    int pos = atomicAdd(&cursor[dst[e]], 1);
    srcs[pos] = src[e];
    const float4* a4 = (const float4*)(eattr + (size_t)e * FE);
    float a[16];
#pragma unroll
    for (int q = 0; q < 4; ++q) {
        float4 v = a4[q];
        a[q * 4 + 0] = v.x; a[q * 4 + 1] = v.y;
        a[q * 4 + 2] = v.z; a[q * 4 + 3] = v.w;
    }
    unsigned hu[8], lu[8];
#pragma unroll
    for (int j = 0; j < 8; ++j) {
        ushort_t h0 = f2bf(a[2 * j]), h1 = f2bf(a[2 * j + 1]);
        ushort_t l0 = f2bf(a[2 * j] - bf2f(h0));
        ushort_t l1 = f2bf(a[2 * j + 1] - bf2f(h1));
        hu[j] = (unsigned)h0 | ((unsigned)h1 << 16);
        lu[j] = (unsigned)l0 | ((unsigned)l1 << 16);
    }
    uint4* ph = (uint4*)(eaH + (size_t)pos * 16);
    uint4* pl = (uint4*)(eaL + (size_t)pos * 16);
    ph[0] = make_uint4(hu[0], hu[1], hu[2], hu[3]);
    ph[1] = make_uint4(hu[4], hu[5], hu[6], hu[7]);
    pl[0] = make_uint4(lu[0], lu[1], lu[2], lu[3]);
    pl[1] = make_uint4(lu[4], lu[5], lu[6], lu[7]);
}

// ---------------------------------------------------------------------------
// Node LSTM weight repack (interleaved i/g) for the fp32 GEMM fused epilogue
// ---------------------------------------------------------------------------
__global__ void repack_k(const float* __restrict__ W, const float* __restrict__ b,
                         float* __restrict__ W2, float* __restrict__ b2, int K) {
    int idx = blockIdx.x * blockDim.x + threadIdx.x;
    if (idx < 512 * K) {
        int r = idx / K, k = idx - r * K;
        int c = r >> 1;
        int rs = (r & 1) ? (512 + c) : c;
        W2[idx] = W[rs * K + k];
    } else if (idx < 512 * K + 512) {
        int r = idx - 512 * K;
        int c = r >> 1;
        int rs = (r & 1) ? (512 + c) : c;
        b2[r] = b[rs];
    }
}

// Edge LSTM weights -> bf16 hi/lo planes [512,16]: out-rows 0..255 = i-gate
// rows 0..255 of edge_W; 256..511 = g-gate rows 512..767.
__global__ void repack_edge_k(const float* __restrict__ W,
                              ushort_t* __restrict__ Wh,
                              ushort_t* __restrict__ Wl) {
    int idx = blockIdx.x * blockDim.x + threadIdx.x;
    if (idx >= 512 * 16) return;
    int r = idx >> 4, k = idx & 15;
    int rs = (r < 256) ? r : (512 + r - 256);
    float v = W[rs * 16 + k];
    ushort_t h = f2bf(v);
    Wh[idx] = h;
    Wl[idx] = f2bf(v - bf2f(h));
}

// fp32 weight [R,K] -> bf16 hi/lo planes
__global__ void convw_k(const float* __restrict__ W, ushort_t* __restrict__ Wh,
                        ushort_t* __restrict__ Wl, int n) {
    int i = blockIdx.x * blockDim.x + threadIdx.x;
    if (i < n) {
        float x = W[i];
        ushort_t h = f2bf(x);
        Wh[i] = h;
        Wl[i] = f2bf(x - bf2f(h));
    }
}

// ---------------------------------------------------------------------------
// Edge LSTM GEMM via MFMA split-bf16: z[E,512] = attr[E,16] @ W[512,16]^T
// (K=16 real; k>=16 fragment half zeroed in-register), fused sig*tanh
// epilogue -> eacsr bf16 [E,256]. Block = 64 rows; wave = 16 rows.
// ---------------------------------------------------------------------------
__global__ __launch_bounds__(256, 2) void edge_gemm_k(
    const ushort_t* __restrict__ Ah, const ushort_t* __restrict__ Al,
    const ushort_t* __restrict__ Bh, const ushort_t* __restrict__ Bl,
    const float* __restrict__ eb, ushort_t* __restrict__ eacsr) {
    int tid = threadIdx.x;
    int w = tid >> 6, l = tid & 63;
    int row0 = blockIdx.x * 64 + w * 16;
    int lr = l & 15, lk = l >> 4;
    bf16x8 ah = {0, 0, 0, 0, 0, 0, 0, 0};
    bf16x8 al = {0, 0, 0, 0, 0, 0, 0, 0};
    if (lk < 2) {
        ah = *(const bf16x8*)(Ah + (size_t)(row0 + lr) * 16 + lk * 8);
        al = *(const bf16x8*)(Al + (size_t)(row0 + lr) * 16 + lk * 8);
    }
    f32x4 acc[32];
#pragma unroll
    for (int i = 0; i < 32; ++i) acc[i] = (f32x4){0.f, 0.f, 0.f, 0.f};
#pragma unroll
    for (int ct = 0; ct < 32; ++ct) {
        bf16x8 bh = {0, 0, 0, 0, 0, 0, 0, 0};
        bf16x8 bl = {0, 0, 0, 0, 0, 0, 0, 0};
        if (lk < 2) {
            bh = *(const bf16x8*)(Bh + (size_t)(ct * 16 + lr) * 16 + lk * 8);
            bl = *(const bf16x8*)(Bl + (size_t)(ct * 16 + lr) * 16 + lk * 8);
        }
        acc[ct] = __builtin_amdgcn_mfma_f32_16x16x32_bf16(ah, bh, acc[ct], 0, 0, 0);
        acc[ct] = __builtin_amdgcn_mfma_f32_16x16x32_bf16(ah, bl, acc[ct], 0, 0, 0);
        acc[ct] = __builtin_amdgcn_mfma_f32_16x16x32_bf16(al, bh, acc[ct], 0, 0, 0);
    }
#pragma unroll
    for (int ct = 0; ct < 16; ++ct) {
        int ci = ct * 16 + lr;  // channel
        float bi = eb[ci], bg = eb[512 + ci];
#pragma unroll
        for (int r = 0; r < 4; ++r) {
            int m = row0 + lk * 4 + r;
            float zi = acc[ct][r] + bi;
            float zg = acc[ct + 16][r] + bg;
            eacsr[(size_t)m * HH + ci] = f2bf(sig_tanh(zi, zg));
        }
    }
}

// ---------------------------------------------------------------------------
// MLP GEMM via MFMA split-bf16, NT: C[M,NN] = A[M,K] @ B[NN,K]^T
// Block 64 rows x 256 cols, grid (ceil(M/64), NN/256).
// mode 0: relu(BN(acc+bias)) -> bf16 hi/lo pair planes (for next GEMM)
// mode 1: relu(acc+bias)     -> fp32
// ---------------------------------------------------------------------------
__global__ __launch_bounds__(256, 2) void gemm_mfma_k(
    const ushort_t* __restrict__ Ah, const ushort_t* __restrict__ Al,
    const ushort_t* __restrict__ Bh, const ushort_t* __restrict__ Bl,
    const float* __restrict__ bias, const float* __restrict__ gamma,
    const float* __restrict__ beta, ushort_t* __restrict__ Ph,
    ushort_t* __restrict__ Pl, float* __restrict__ Cf, int M, int NN, int K,
    int mode) {
    int tid = threadIdx.x;
    int w = tid >> 6, l = tid & 63;
    int row0 = blockIdx.x * 64 + w * 16;
    int col0 = blockIdx.y * 256;
    int lr = l & 15, lk = l >> 4;
    f32x4 acc[16];
#pragma unroll
    for (int i = 0; i < 16; ++i) acc[i] = (f32x4){0.f, 0.f, 0.f, 0.f};
    const ushort_t* arh = Ah + (size_t)(row0 + lr) * K + lk * 8;
    const ushort_t* arl = Al + (size_t)(row0 + lr) * K + lk * 8;
    const ushort_t* brh = Bh + (size_t)(col0 + lr) * K + lk * 8;
    const ushort_t* brl = Bl + (size_t)(col0 + lr) * K + lk * 8;
    for (int kc = 0; kc < K; kc += 32) {
        bf16x8 ah = *(const bf16x8*)(arh + kc);
        bf16x8 al = *(const bf16x8*)(arl + kc);
#pragma unroll
        for (int ct = 0; ct < 16; ++ct) {
            bf16x8 bh = *(const bf16x8*)(brh + (size_t)ct * 16 * K + kc);
            bf16x8 bl = *(const bf16x8*)(brl + (size_t)ct * 16 * K + kc);
            acc[ct] = __builtin_amdgcn_mfma_f32_16x16x32_bf16(ah, bh, acc[ct], 0, 0, 0);
            acc[ct] = __builtin_amdgcn_mfma_f32_16x16x32_bf16(ah, bl, acc[ct], 0, 0, 0);
            acc[ct] = __builtin_amdgcn_mfma_f32_16x16x32_bf16(al, bh, acc[ct], 0, 0, 0);
        }
    }
    const float bn_rs = rsqrtf(1.f + 1e-5f);
#pragma unroll
    for (int ct = 0; ct < 16; ++ct) {
        int c = col0 + ct * 16 + lr;
        float bs = bias[c];
        float sc = 1.f, sh = 0.f;
        if (mode == 0) {
            sc = gamma[c] * bn_rs;
            sh = beta[c];
        }
#pragma unroll
        for (int r = 0; r < 4; ++r) {
            int m = row0 + lk * 4 + r;
            if (m >= M) continue;
            float v = acc[ct][r] + bs;
            if (mode == 0) v = v * sc + sh;
            v = fmaxf(v, 0.f);
            if (mode == 0) {
                ushort_t h = f2bf(v);
                Ph[(size_t)m * NN + c] = h;
                Pl[(size_t)m * NN + c] = f2bf(v - bf2f(h));
            } else {
                Cf[(size_t)m * NN + c] = v;
            }
        }
    }
}

// ---------------------------------------------------------------------------
// GENConv edge pass (gather form, softmax m=0 shift). eacsr bf16 CSR-ordered;
// output packed as bf16 hi/lo pair planes (next GEMM's A).
// ---------------------------------------------------------------------------
#define NPB 8
__global__ __launch_bounds__(256, 8) void genconv_edge_k(
    const float* __restrict__ hin, const ushort_t* __restrict__ eacsr,
    const int* __restrict__ srcs, const int* __restrict__ rowst,
    const float* __restrict__ tptr, ushort_t* __restrict__ Oh,
    ushort_t* __restrict__ Ol) {
    int tid = threadIdx.x;  // channel
    float tscale = tptr[0];
    int n0 = blockIdx.x * NPB;
    for (int u = 0; u < NPB; ++u) {
        int n = n0 + u;
        if (n >= N_NODES) break;
        int s0 = rowst[n], s1 = rowst[n + 1];
        float hself = hin[(size_t)n * HH + tid];
        float accE0 = 0.f, accWE0 = 0.f, accE1 = 0.f, accWE1 = 0.f;
        int j = s0;
        for (; j + 1 < s1; j += 2) {
            int sn0 = srcs[j], sn1 = srcs[j + 1];
            float ea0 = bf2f(eacsr[(size_t)j * HH + tid]);
            float ea1 = bf2f(eacsr[(size_t)(j + 1) * HH + tid]);
            float h0v = hin[(size_t)sn0 * HH + tid];
            float h1v = hin[(size_t)sn1 * HH + tid];
            float m0 = fmaxf(h0v + ea0, 0.f) + 1e-7f;
            float m1 = fmaxf(h1v + ea1, 0.f) + 1e-7f;
            float p0 = __expf(tscale * m0);
            float p1 = __expf(tscale * m1);
            accE0 += p0;
            accWE0 += p0 * m0;
            accE1 += p1;
            accWE1 += p1 * m1;
        }
        if (j < s1) {
            int sn = srcs[j];
            float eav = bf2f(eacsr[(size_t)j * HH + tid]);
            float hv = hin[(size_t)sn * HH + tid];
            float m0 = fmaxf(hv + eav, 0.f) + 1e-7f;
            float p0 = __expf(tscale * m0);
            accE0 += p0;
            accWE0 += p0 * m0;
        }
        float v = hself + (accWE0 + accWE1) / (accE0 + accE1 + 1e-16f);
        ushort_t h = f2bf(v);
        Oh[(size_t)n * HH + tid] = h;
        Ol[(size_t)n * HH + tid] = f2bf(v - bf2f(h));
    }
}

// ---------------------------------------------------------------------------
// fp32 GEMM (node LSTM only, K=64, fused sigmoid*tanh epilogue)
// ---------------------------------------------------------------------------
#define TM 128
#define TN 128
#define KB 16
__global__ __launch_bounds__(256, 2) void gemm_nt_k(
    const float* __restrict__ A, const float* __restrict__ B,
    const float* __restrict__ bias, float* __restrict__ C, int M, int NN,
    int K) {
    __shared__ float As[KB][TM + 4];
    __shared__ float Bs[KB][TN + 4];
    int tid = threadIdx.x;
    int row0 = blockIdx.x * TM, col0 = blockIdx.y * TN;
    int tx = tid & 15, ty = tid >> 4;
    int lr = tid >> 2;
    int lc = (tid & 3) * 4;
    float4 va[2], vb[2];
#pragma unroll
    for (int h = 0; h < 2; ++h) {
        int r = lr + h * 64;
        int gr = row0 + r;
        va[h] = (gr < M) ? *(const float4*)&A[(size_t)gr * K + lc]
                         : make_float4(0.f, 0.f, 0.f, 0.f);
        vb[h] = *(const float4*)&B[(size_t)(col0 + r) * K + lc];
    }
    float acc[8][8] = {{0.f}};
    for (int k0 = 0; k0 < K; k0 += KB) {
#pragma unroll
        for (int h = 0; h < 2; ++h) {
            int r = lr + h * 64;
            As[lc + 0][r] = va[h].x;
            As[lc + 1][r] = va[h].y;
            As[lc + 2][r] = va[h].z;
            As[lc + 3][r] = va[h].w;
            Bs[lc + 0][r] = vb[h].x;
            Bs[lc + 1][r] = vb[h].y;
            Bs[lc + 2][r] = vb[h].z;
            Bs[lc + 3][r] = vb[h].w;
        }
        __syncthreads();
        int k1 = k0 + KB;
        if (k1 < K) {
#pragma unroll
            for (int h = 0; h < 2; ++h) {
                int r = lr + h * 64;
                int gr = row0 + r;
                va[h] = (gr < M)
                            ? *(const float4*)&A[(size_t)gr * K + k1 + lc]
                            : make_float4(0.f, 0.f, 0.f, 0.f);
                vb[h] = *(const float4*)&B[(size_t)(col0 + r) * K + k1 + lc];
            }
        }
#pragma unroll
        for (int k = 0; k < KB; ++k) {
            float4 a0 = *(const float4*)&As[k][ty * 4];
            float4 a1 = *(const float4*)&As[k][64 + ty * 4];
            float4 b0 = *(const float4*)&Bs[k][tx * 4];
            float4 b1 = *(const float4*)&Bs[k][64 + tx * 4];
            float av[8] = {a0.x, a0.y, a0.z, a0.w, a1.x, a1.y, a1.z, a1.w};
            float bv[8] = {b0.x, b0.y, b0.z, b0.w, b1.x, b1.y, b1.z, b1.w};
#pragma unroll
            for (int i = 0; i < 8; ++i)
#pragma unroll
                for (int j = 0; j < 8; ++j) acc[i][j] += av[i] * bv[j];
        }
        __syncthreads();
    }
#pragma unroll
    for (int gj = 0; gj < 2; ++gj) {
        int nb = col0 + gj * 64 + tx * 4;
        float bs[4];
#pragma unroll
        for (int j = 0; j < 4; ++j) bs[j] = bias[nb + j];
#pragma unroll
        for (int gi = 0; gi < 2; ++gi) {
#pragma unroll
            for (int i2 = 0; i2 < 4; ++i2) {
                int m = row0 + gi * 64 + ty * 4 + i2;
                if (m >= M) continue;
                int i = gi * 4 + i2;
                float y0 = acc[i][gj * 4 + 0] + bs[0];
                float y1 = acc[i][gj * 4 + 1] + bs[1];
                float y2 = acc[i][gj * 4 + 2] + bs[2];
                float y3 = acc[i][gj * 4 + 3] + bs[3];
                float2 o;
                o.x = sig_tanh(y0, y1);
                o.y = sig_tanh(y2, y3);
                *(float2*)&C[(size_t)m * (NN / 2) + nb / 2] = o;
            }
        }
    }
}

// ---------------------------------------------------------------------------
// Instance norm (block = graph, thread = channel)
// ---------------------------------------------------------------------------
__device__ __forceinline__ int lowerb(const int* a, int n, int key) {
    int lo = 0, hi = n;
    while (lo < hi) {
        int mid = (lo + hi) >> 1;
        if (a[mid] < key) lo = mid + 1;
        else hi = mid;
    }
    return lo;
}

__global__ __launch_bounds__(256) void inst_norm_k(
    const float* __restrict__ x, const int* __restrict__ batch,
    float* __restrict__ y) {
    __shared__ int sS, sE;
    int g = blockIdx.x, t = threadIdx.x;
    if (t == 0) {
        sS = lowerb(batch, N_NODES, g);
        sE = lowerb(batch, N_NODES, g + 1);
    }
    __syncthreads();
    int s = sS, e = sE;
    float sum = 0.f, ss = 0.f;
    for (int n = s; n < e; ++n) {
        float v = x[(size_t)n * HH + t];
        sum += v;
        ss += v * v;
    }
    float c = (float)((e - s) > 0 ? (e - s) : 1);
    float mean = sum / c;
    float var = ss / c - mean * mean;
    float inv = rsqrtf(var + 1e-5f);
    for (int n = s; n < e; ++n) {
        float v = x[(size_t)n * HH + t];
        y[(size_t)n * HH + t] = (v - mean) * inv;
    }
}

// ---------------------------------------------------------------------------
// Fused inst-norm + segment-max pool + linear + sigmoid (block = graph)
// ---------------------------------------------------------------------------
__global__ __launch_bounds__(256) void inpool_k(
    const float* __restrict__ x, const int* __restrict__ batch,
    const float* __restrict__ lw, const float* __restrict__ lb,
    float* __restrict__ out) {
    __shared__ float pooled[HH];
    __shared__ int sS, sE;
    int g = blockIdx.x, t = threadIdx.x;
    if (t == 0) {
        sS = lowerb(batch, N_NODES, g);
        sE = lowerb(batch, N_NODES, g + 1);
    }
    __syncthreads();
    int s = sS, e = sE;
    float sum = 0.f, ss = 0.f;
    for (int n = s; n < e; ++n) {
        float v = x[(size_t)n * HH + t];
        sum += v;
        ss += v * v;
    }
    float c = (float)((e - s) > 0 ? (e - s) : 1);
    float mean = sum / c;
    float var = ss / c - mean * mean;
    float inv = rsqrtf(var + 1e-5f);
    float m = -3.0e38f;
    for (int n = s; n < e; ++n) {
        float v = (x[(size_t)n * HH + t] - mean) * inv;
        m = fmaxf(m, v);
    }
    pooled[t] = (e > s) ? m : 0.f;
    __syncthreads();
    if (t < 10) {
        float acc = lb[t];
        for (int k = 0; k < HH; ++k) acc += pooled[k] * lw[t * HH + k];
        out[g * 10 + t] = fast_sigmoid(acc);
    }
}

// ---------------------------------------------------------------------------
extern "C" void kernel_launch(void* const* d_in, const int* in_sizes, int n_in,
                              void* d_out, int out_size, void* d_ws,
                              size_t ws_size, hipStream_t stream) {
    const float* x      = (const float*)d_in[0];
    const int*   ei     = (const int*)d_in[1];
    const float* eattr  = (const float*)d_in[2];
    const int*   batch  = (const int*)d_in[3];
    const float* nodeW  = (const float*)d_in[4];
    const float* nodeb  = (const float*)d_in[5];
    const float* edgeW  = (const float*)d_in[6];
    const float* edgeb  = (const float*)d_in[7];
    const float* t1     = (const float*)d_in[8];
    const float* g1w1   = (const float*)d_in[9];
    const float* g1b1   = (const float*)d_in[10];
    const float* g1g    = (const float*)d_in[11];
    const float* g1be   = (const float*)d_in[12];
    const float* g1w2   = (const float*)d_in[13];
    const float* g1b2   = (const float*)d_in[14];
    const float* t2     = (const float*)d_in[15];
    const float* g2w1   = (const float*)d_in[16];
    const float* g2b1   = (const float*)d_in[17];
    const float* g2g    = (const float*)d_in[18];
    const float* g2be   = (const float*)d_in[19];
    const float* g2w2   = (const float*)d_in[20];
    const float* g2b2   = (const float*)d_in[21];
    const float* linw   = (const float*)d_in[22];
    const float* linb   = (const float*)d_in[23];
    float* out = (float*)d_out;

    const int* srcA = ei;
    const int* dstA = ei + N_EDGES;

    auto AL = [](size_t b) { return (b + 255) & ~(size_t)255; };
    char* p = (char*)d_ws;
    // F0: fp32 [N,256] (node-LSTM out / inst-norm-1 out)
    float* F0 = (float*)p;
    p += AL((size_t)N_NODES * HH * 4);
    // EA union region (temporally disjoint occupants):
    //   phase 1: eaH/eaL bf16 [E,16]            (scatter -> edge_gemm)
    //   phase 2: F1h/F1l bf16 [MPAD,256]        (conv -> gemm1)
    //   phase 3: F1f fp32 [N,256]               (gemm2 -> instnorm/inpool)
    char* EA = p;
    ushort_t* eaH = (ushort_t*)EA;
    ushort_t* eaL = (ushort_t*)(EA + AL((size_t)N_EDGES * 16 * 2));
    ushort_t* F1h = (ushort_t*)EA;
    ushort_t* F1l = (ushort_t*)(EA + AL((size_t)MPAD * HH * 2));
    float* F1f = (float*)EA;
    size_t sp1 = 2 * AL((size_t)N_EDGES * 16 * 2);
    size_t sp2 = 2 * AL((size_t)MPAD * HH * 2);
    size_t sp3 = AL((size_t)N_NODES * HH * 4);
    size_t spm = sp1 > sp2 ? sp1 : sp2;
    if (sp3 > spm) spm = sp3;
    p += AL(spm);
    // F2 pair planes [MPAD,512]
    ushort_t* F2h = (ushort_t*)p;
    p += AL((size_t)MPAD * 512 * 2);
    ushort_t* F2l = (ushort_t*)p;
    p += AL((size_t)MPAD * 512 * 2);
    // eacsr bf16 [E,256]
    ushort_t* eacsr = (ushort_t*)p;
    p += AL((size_t)N_EDGES * HH * 2);
    // weight planes
    ushort_t* w11h = (ushort_t*)p; p += AL(512 * 256 * 2);
    ushort_t* w11l = (ushort_t*)p; p += AL(512 * 256 * 2);
    ushort_t* w12h = (ushort_t*)p; p += AL(256 * 512 * 2);
    ushort_t* w12l = (ushort_t*)p; p += AL(256 * 512 * 2);
    ushort_t* w21h = (ushort_t*)p; p += AL(512 * 256 * 2);
    ushort_t* w21l = (ushort_t*)p; p += AL(512 * 256 * 2);
    ushort_t* w22h = (ushort_t*)p; p += AL(256 * 512 * 2);
    ushort_t* w22l = (ushort_t*)p; p += AL(256 * 512 * 2);
    ushort_t* weh  = (ushort_t*)p; p += AL(512 * 16 * 2);
    ushort_t* wel  = (ushort_t*)p; p += AL(512 * 16 * 2);
    // node LSTM repack (fp32)
    float* W2n = (float*)p; p += AL(512 * 64 * 4);
    float* b2n = (float*)p; p += AL(512 * 4);
    // ints
    int* cnt    = (int*)p; p += AL((size_t)N_NODES * 4);
    int* cursor = (int*)p; p += AL((size_t)N_NODES * 4);
    int* rowst  = (int*)p; p += AL(((size_t)N_NODES + 1) * 4);
    int* srcs   = (int*)p; p += AL((size_t)N_EDGES * 4);
    int* bsum   = (int*)p; p += AL(128 * 4);
    // total ~249.6 MB (< 256 MiB; r7's 257.6 MiB overflowed and faulted)

    const int NSCB = (N_NODES + 255) / 256;  // 79

    // --- CSR build + attr plane scatter ---
    hipMemsetAsync(cnt, 0, N_NODES * sizeof(int), stream);
    hist_k<<<(N_EDGES + 255) / 256, 256, 0, stream>>>(dstA, cnt);
    scan1_k<<<NSCB, 256, 0, stream>>>(cnt, rowst, bsum);
    scan2_k<<<1, 128, 0, stream>>>(bsum, NSCB);
    scan3_k<<<NSCB, 256, 0, stream>>>(cnt, bsum, rowst, cursor);
    scatter_k<<<(N_EDGES + 255) / 256, 256, 0, stream>>>(srcA, dstA, eattr,
                                                         cursor, srcs, eaH, eaL);

    // --- weight conversions ---
    repack_k<<<(512 * 64 + 512 + 255) / 256, 256, 0, stream>>>(nodeW, nodeb,
                                                               W2n, b2n, 64);
    repack_edge_k<<<(512 * 16 + 255) / 256, 256, 0, stream>>>(edgeW, weh, wel);
    convw_k<<<512, 256, 0, stream>>>(g1w1, w11h, w11l, 512 * 256);
    convw_k<<<512, 256, 0, stream>>>(g1w2, w12h, w12l, 256 * 512);
    convw_k<<<512, 256, 0, stream>>>(g2w1, w21h, w21l, 512 * 256);
    convw_k<<<512, 256, 0, stream>>>(g2w2, w22h, w22l, 256 * 512);

    // --- edge LSTM (MFMA) -> eacsr (consumes eaH/eaL before F1 reuse) ---
    edge_gemm_k<<<N_EDGES / 64, 256, 0, stream>>>(eaH, eaL, weh, wel, edgeb,
                                                  eacsr);

    // --- node LSTM (fp32 GEMM, fused activation) -> F0 ---
    gemm_nt_k<<<dim3((N_NODES + TM - 1) / TM, 512 / TN), 256, 0, stream>>>(
        x, W2n, b2n, F0, N_NODES, 512, 64);

    dim3 g1grid((N_NODES + 63) / 64, 2);  // NN=512
    dim3 g2grid((N_NODES + 63) / 64, 1);  // NN=256

    // --- GENConv 1 ---
    genconv_edge_k<<<(N_NODES + NPB - 1) / NPB, 256, 0, stream>>>(
        F0, eacsr, srcs, rowst, t1, F1h, F1l);
    gemm_mfma_k<<<g1grid, 256, 0, stream>>>(F1h, F1l, w11h, w11l, g1b1, g1g,
                                            g1be, F2h, F2l, nullptr, N_NODES,
                                            512, 256, 0);
    gemm_mfma_k<<<g2grid, 256, 0, stream>>>(F2h, F2l, w12h, w12l, g1b2, g1b2,
                                            g1b2, nullptr, nullptr, F1f,
                                            N_NODES, 256, 512, 1);
    inst_norm_k<<<GG, 256, 0, stream>>>(F1f, batch, F0);

    // --- GENConv 2 ---
    genconv_edge_k<<<(N_NODES + NPB - 1) / NPB, 256, 0, stream>>>(
        F0, eacsr, srcs, rowst, t2, F1h, F1l);
    gemm_mfma_k<<<g1grid, 256, 0, stream>>>(F1h, F1l, w21h, w21l, g2b1, g2g,
                                            g2be, F2h, F2l, nullptr, N_NODES,
                                            512, 256, 0);
    gemm_mfma_k<<<g2grid, 256, 0, stream>>>(F2h, F2l, w22h, w22l, g2b2, g2b2,
                                            g2b2, nullptr, nullptr, F1f,
                                            N_NODES, 256, 512, 1);

    // --- fused inst-norm + pool + linear + sigmoid ---
    inpool_k<<<GG, 256, 0, stream>>>(F1f, batch, linw, linb, out);
}